// Round 10
// baseline (280.410 us; speedup 1.0000x reference)
//
#include <hip/hip_runtime.h>
#include <hip/hip_fp16.h>
#include <cstdint>
#include <cstddef>

// SlotAttention, round 9.
//  - fused_attn_f16 v3: async global_load_lds staging (pre-swizzled global
//    source -> linear LDS, XOR (row&15)<<4), 4 chunks/block double-buffered
//    with counted vmcnt(8) + raw s_barrier (T3/T4 pattern). 512 blocks,
//    2 blocks/CU co-resident, 76KB LDS.
//  - xh_prep / convert_weights / slot_update unchanged (r6-r8 proven).

#define NTOK 4096
#define DDIM 256
#define NSLOT 8
#define NBATCH 32
#define CH 64                    // tokens per chunk
#define NCHK 64                  // chunks per batch
#define SROWS (NBATCH * NSLOT)
#define NROWS (NBATCH * NTOK)
#define SCALE 0.0625f
#define LN_EPS_C 1e-5f
#define ATTN_EPS_C 1e-8f

__device__ __forceinline__ void wave_reduce2(float& s, float& ss) {
#pragma unroll
  for (int off = 32; off > 0; off >>= 1) {
    s  += __shfl_down(s, off, 64);
    ss += __shfl_down(ss, off, 64);
  }
}
__device__ __forceinline__ void wave_reduce2_xor(float& s, float& ss) {
#pragma unroll
  for (int off = 32; off > 0; off >>= 1) {
    s  += __shfl_xor(s, off, 64);
    ss += __shfl_xor(ss, off, 64);
  }
}

// transpose 6 weight matrices to fp16; plain-convert Wk to fp16 (r6 proven).
__global__ __launch_bounds__(256) void convert_weights_k(
    const float* __restrict__ Wq, const float* __restrict__ Wv,
    const float* __restrict__ Wih, const float* __restrict__ Whh,
    const float* __restrict__ W1, const float* __restrict__ W2,
    const float* __restrict__ Wk, __half* __restrict__ WqT,
    __half* __restrict__ WvT, __half* __restrict__ WihT,
    __half* __restrict__ WhhT, __half* __restrict__ W1T,
    __half* __restrict__ W2T, __half* __restrict__ Wk_h) {
  __shared__ float tile[32][33];
  int bz = blockIdx.x;
  int tx = threadIdx.x & 31, ty = threadIdx.x >> 5;
  if (bz >= 80) {
    int ro = (bz - 80) * 32, cd = blockIdx.y * 32;
#pragma unroll
    for (int p = 0; p < 32; p += 8)
      Wk_h[(size_t)(ro + ty + p) * DDIM + cd + tx] =
          __float2half(Wk[(size_t)(ro + ty + p) * DDIM + cd + tx]);
    return;
  }
  const float* in; __half* out; int O, bo;
  if (bz < 8)       { in = Wq;  out = WqT;  O = 256; bo = bz; }
  else if (bz < 16) { in = Wv;  out = WvT;  O = 256; bo = bz - 8; }
  else if (bz < 40) { in = Wih; out = WihT; O = 768; bo = bz - 16; }
  else if (bz < 64) { in = Whh; out = WhhT; O = 768; bo = bz - 40; }
  else if (bz < 72) { in = W1;  out = W1T;  O = 256; bo = bz - 64; }
  else              { in = W2;  out = W2T;  O = 256; bo = bz - 72; }
  int ro = bo * 32, cd = blockIdx.y * 32;
#pragma unroll
  for (int p = 0; p < 32; p += 8)
    tile[ty + p][tx] = in[(size_t)(ro + ty + p) * DDIM + cd + tx];
  __syncthreads();
#pragma unroll
  for (int p = 0; p < 32; p += 8)
    out[(size_t)(cd + ty + p) * O + ro + tx] = __float2half(tile[tx][ty + p]);
}

// streaming LN -> fp16. wave per row (64 lanes x float4 = 256 floats).
__global__ __launch_bounds__(256) void xh_prep_k(
    const float* __restrict__ X, const float* __restrict__ g,
    const float* __restrict__ be, __half* __restrict__ xh) {
  int row = blockIdx.x * 4 + (threadIdx.x >> 6);
  int lane = threadIdx.x & 63;
  float4 a = *(const float4*)(X + (size_t)row * DDIM + lane * 4);
  float s = a.x + a.y + a.z + a.w;
  float ss = a.x * a.x + a.y * a.y + a.z * a.z + a.w * a.w;
  wave_reduce2_xor(s, ss);
  float m = s * (1.f / DDIM);
  float rs = rsqrtf(ss * (1.f / DDIM) - m * m + LN_EPS_C);
  float4 gv = *(const float4*)(g + lane * 4);
  float4 bev = *(const float4*)(be + lane * 4);
  union { __half2 h[2]; uint2 u; } pk;
  pk.h[0] = __floats2half2_rn((a.x - m) * rs * gv.x + bev.x,
                              (a.y - m) * rs * gv.y + bev.y);
  pk.h[1] = __floats2half2_rn((a.z - m) * rs * gv.z + bev.z,
                              (a.w - m) * rs * gv.w + bev.w);
  *(uint2*)(xh + (size_t)row * DDIM + lane * 4) = pk.u;
}

// token pass v3: block = (b, group of 4 chunks), 256 threads.
// DMA-staged swizzled tiles, double-buffered; counted vmcnt; raw barriers.
__global__ __launch_bounds__(256) void fused_attn_f16_k(
    const __half* __restrict__ xh, const float* __restrict__ qk,
    const float* __restrict__ qkb, float* __restrict__ attn_out,
    float* __restrict__ S_part, __half* __restrict__ u_part, int write_attn) {
  __shared__ __align__(16) char sx[2][CH * 512];  // 64 KB: swizzled fp16 tiles
  __shared__ __half2 sqh[NSLOT][128];             // 4 KB: qk fp16
  __shared__ float part[4][NSLOT][CH];            // 8 KB (sa aliases part[0])
#define SA(i, j) part[0][i][j]
  int b = blockIdx.x, t = threadIdx.x;
  int c0 = blockIdx.y * 4;
  int lane = t & 63, w = t >> 6;

  // stage qk as fp16 (ds_writes; drained by first lgkmcnt(0))
#pragma unroll
  for (int r2 = 0; r2 < 4; ++r2) {
    int idx = r2 * 256 + t;
    int i = idx >> 7, d2 = idx & 127;
    const float* qr = qk + ((size_t)b * NSLOT + i) * DDIM + d2 * 2;
    sqh[i][d2] = __floats2half2_rn(qr[0], qr[1]);
  }

  const size_t rowb = (size_t)b * NTOK;

  // async DMA of one 64x256 fp16 tile into LDS buffer `buf`, source
  // pre-swizzled so LDS linear layout holds swizzled rows (T2/m173).
  auto issue = [&](int buf, int chunk) {
#pragma unroll
    for (int k = 0; k < 8; ++k) {
      int seg = w * 8 + k;                 // wave-uniform
      int L = (seg << 10) + lane * 16;     // byte offset in tile
      int row = L >> 9, col = L & 511;
      int scol = col ^ ((row & 15) << 4);
      const __half* src =
          xh + (rowb + (size_t)chunk * CH + row) * DDIM + (scol >> 1);
      __builtin_amdgcn_global_load_lds(
          (const __attribute__((address_space(1))) void*)src,
          (__attribute__((address_space(3))) void*)(&sx[buf][seg << 10]),
          16, 0, 0);
    }
  };

  auto compute = [&](int buf, int chunk) {
    const char* sb = sx[buf];
    // phase A: tj = t&31 -> tokens tj, tj+32; qd = dim-slice of 32
    {
      int tj = t & 31, qd = (t >> 5) & 7;
      int sw = (tj & 15) << 4;             // (tj+32)&15 == tj&15
      float2 xa[16], xb[16];
#pragma unroll
      for (int d2 = 0; d2 < 16; ++d2) {
        int ca = qd * 64 + d2 * 4;
        xa[d2] = __half22float2(*(const __half2*)(sb + tj * 512 + (ca ^ sw)));
        xb[d2] =
            __half22float2(*(const __half2*)(sb + (tj + 32) * 512 + (ca ^ sw)));
      }
      bool lo = (t & 63) < 32;
#pragma unroll
      for (int i = 0; i < NSLOT; ++i) {
        float pa = 0.f, pb = 0.f;
#pragma unroll
        for (int d2 = 0; d2 < 16; ++d2) {
          float2 qf = __half22float2(sqh[i][qd * 16 + d2]);
          pa = fmaf(xa[d2].x, qf.x, fmaf(xa[d2].y, qf.y, pa));
          pb = fmaf(xb[d2].x, qf.x, fmaf(xb[d2].y, qf.y, pb));
        }
        pa += __shfl_down(pa, 32, 64);     // combine qd pair within wave
        pb += __shfl_down(pb, 32, 64);
        if (lo) { part[w][i][tj] = pa; part[w][i][tj + 32] = pb; }
      }
    }
    asm volatile("s_waitcnt lgkmcnt(0)" ::: "memory");
    __builtin_amdgcn_s_barrier();
    // phase B: wave 0, token t
    if (t < CH) {
      float dots[NSLOT], mx = -1e30f;
#pragma unroll
      for (int i = 0; i < NSLOT; ++i) {
        dots[i] = part[0][i][t] + part[1][i][t] + part[2][i][t] +
                  part[3][i][t] + qkb[b * NSLOT + i];
        mx = fmaxf(mx, dots[i]);
      }
      float sum = 0.f;
#pragma unroll
      for (int i = 0; i < NSLOT; ++i) {
        dots[i] = expf(dots[i] - mx);
        sum += dots[i];
      }
      float inv = 1.f / sum;
#pragma unroll
      for (int i = 0; i < NSLOT; ++i) {
        float a = dots[i] * inv;
        if (write_attn)
          attn_out[((size_t)b * NSLOT + i) * NTOK + chunk * CH + t] = a;
        dots[i] = a + ATTN_EPS_C;
      }
#pragma unroll
      for (int i = 0; i < NSLOT; ++i) {
        float ps = dots[i];
#pragma unroll
        for (int off = 32; off > 0; off >>= 1) ps += __shfl_down(ps, off, 64);
        if (t == 0) S_part[((size_t)b * NCHK + chunk) * NSLOT + i] = ps;
      }
      // all part[] reads done above; safe to overwrite part[0] region
#pragma unroll
      for (int i = 0; i < NSLOT; ++i) SA(i, t) = dots[i];
    }
    asm volatile("s_waitcnt lgkmcnt(0)" ::: "memory");
    __builtin_amdgcn_s_barrier();
    // phase C: thread = dim t
    {
      float acc[NSLOT] = {};
#pragma unroll 8
      for (int jj = 0; jj < CH; ++jj) {
        int ad = jj * 512 + ((2 * t) ^ ((jj & 15) << 4));
        float x = __half2float(*(const __half*)(sb + ad));
#pragma unroll
        for (int i = 0; i < NSLOT; ++i) acc[i] = fmaf(x, SA(i, jj), acc[i]);
      }
      __half* upb = u_part + (((size_t)b * NCHK + chunk) * NSLOT) * DDIM + t;
#pragma unroll
      for (int i = 0; i < NSLOT; ++i)
        upb[(size_t)i * DDIM] = __float2half(acc[i]);
    }
  };

  // pipeline: issue 2 tiles up front; keep 1 tile in flight thereafter.
  issue(0, c0);
  issue(1, c0 + 1);
  asm volatile("s_waitcnt vmcnt(8) lgkmcnt(0)" ::: "memory");
  __builtin_amdgcn_s_barrier();
  compute(0, c0);
  asm volatile("s_waitcnt lgkmcnt(0)" ::: "memory");
  __builtin_amdgcn_s_barrier();
  issue(0, c0 + 2);
  asm volatile("s_waitcnt vmcnt(8)" ::: "memory");
  __builtin_amdgcn_s_barrier();
  compute(1, c0 + 1);
  asm volatile("s_waitcnt lgkmcnt(0)" ::: "memory");
  __builtin_amdgcn_s_barrier();
  issue(1, c0 + 3);
  asm volatile("s_waitcnt vmcnt(8)" ::: "memory");
  __builtin_amdgcn_s_barrier();
  compute(0, c0 + 2);
  asm volatile("s_waitcnt lgkmcnt(0)" ::: "memory");
  __builtin_amdgcn_s_barrier();
  asm volatile("s_waitcnt vmcnt(0)" ::: "memory");
  __builtin_amdgcn_s_barrier();
  compute(1, c0 + 3);
#undef SA
}

// slot path, 1024 threads: o = t&255, ks = t>>8. fp16 weights. (r6-r8 proven)
__global__ __launch_bounds__(1024) void slot_update_k(
    const __half* __restrict__ u_part, const float* __restrict__ S_part,
    const float* __restrict__ slots_in, const __half* __restrict__ WvT,
    const float* __restrict__ bv, const __half* __restrict__ WihT,
    const __half* __restrict__ WhhT, const float* __restrict__ b_ih,
    const float* __restrict__ b_hh, const float* __restrict__ g_ff,
    const float* __restrict__ be_ff, const __half* __restrict__ W1T,
    const float* __restrict__ b1, const __half* __restrict__ W2T,
    const float* __restrict__ b2, const float* __restrict__ g_sl,
    const float* __restrict__ be_sl, const __half* __restrict__ WqT,
    const float* __restrict__ bq, const __half* __restrict__ Wk_h,
    const float* __restrict__ bk, const float* __restrict__ noise,
    const float* __restrict__ mu, const float* __restrict__ logsig,
    float* __restrict__ slots_out, float* __restrict__ qk,
    float* __restrict__ qkb_out, int init, int compute_qk) {
  __shared__ float red[4][6][DDIM];
  __shared__ float su[DDIM], sh[DDIM], supd[DDIM], v1[DDIM], v2[DDIM];
  __shared__ float scal[16];
  int r = blockIdx.x, t = threadIdx.x;
  int b = r >> 3, i = r & 7;
  int o = t & 255, ks = t >> 8;
  int lane = t & 63, wid = t >> 6;
  if (init) {
    if (ks == 0) {
      float ns = mu[o] + expf(logsig[o]) * noise[(size_t)r * DDIM + o];
      slots_out[(size_t)r * DDIM + o] = ns;
      v2[o] = ns;
    }
    __syncthreads();
  } else {
    {
      float up = 0.f;
      const __half* upp =
          u_part + (((size_t)b * NCHK + ks * 16) * NSLOT + i) * DDIM + o;
#pragma unroll
      for (int cc = 0; cc < 16; ++cc)
        up += __half2float(upp[(size_t)cc * (NSLOT * DDIM)]);
      red[ks][0][o] = up;
    }
    if (t < 64) {
      float sp = S_part[((size_t)b * NCHK + t) * NSLOT + i];
#pragma unroll
      for (int off = 32; off > 0; off >>= 1) sp += __shfl_down(sp, off, 64);
      if (t == 0) scal[0] = sp;
    }
    if (ks == 0) sh[o] = slots_in[(size_t)r * DDIM + o];
    __syncthreads();
    if (ks == 0) {
      float invS = 1.f / scal[0];
      su[o] = (red[0][0][o] + red[1][0][o] + red[2][0][o] + red[3][0][o]) * invS;
    }
    __syncthreads();
    {
      float p = 0.f;
      const __half* wp = WvT + (size_t)(ks * 64) * DDIM + o;
#pragma unroll 8
      for (int dd = 0; dd < 64; ++dd)
        p = fmaf(su[ks * 64 + dd], __half2float(wp[(size_t)dd * DDIM]), p);
      red[ks][0][o] = p;
    }
    __syncthreads();
    if (ks == 0)
      supd[o] = bv[o] + red[0][0][o] + red[1][0][o] + red[2][0][o] + red[3][0][o];
    __syncthreads();
    {
      float p0 = 0, p1 = 0, p2 = 0, p3 = 0, p4 = 0, p5 = 0;
      const __half* pi = WihT + (size_t)(ks * 64) * (3 * DDIM) + o;
      const __half* ph = WhhT + (size_t)(ks * 64) * (3 * DDIM) + o;
#pragma unroll 4
      for (int dd = 0; dd < 64; ++dd) {
        float ud = supd[ks * 64 + dd], hd = sh[ks * 64 + dd];
        size_t off = (size_t)dd * (3 * DDIM);
        p0 = fmaf(ud, __half2float(pi[off]), p0);
        p1 = fmaf(ud, __half2float(pi[off + DDIM]), p1);
        p2 = fmaf(ud, __half2float(pi[off + 2 * DDIM]), p2);
        p3 = fmaf(hd, __half2float(ph[off]), p3);
        p4 = fmaf(hd, __half2float(ph[off + DDIM]), p4);
        p5 = fmaf(hd, __half2float(ph[off + 2 * DDIM]), p5);
      }
      red[ks][0][o] = p0; red[ks][1][o] = p1; red[ks][2][o] = p2;
      red[ks][3][o] = p3; red[ks][4][o] = p4; red[ks][5][o] = p5;
    }
    __syncthreads();
    if (ks == 0) {
      float air = b_ih[o] + red[0][0][o] + red[1][0][o] + red[2][0][o] + red[3][0][o];
      float aiz = b_ih[DDIM + o] + red[0][1][o] + red[1][1][o] + red[2][1][o] + red[3][1][o];
      float ain = b_ih[2 * DDIM + o] + red[0][2][o] + red[1][2][o] + red[2][2][o] + red[3][2][o];
      float ahr = b_hh[o] + red[0][3][o] + red[1][3][o] + red[2][3][o] + red[3][3][o];
      float ahz = b_hh[DDIM + o] + red[0][4][o] + red[1][4][o] + red[2][4][o] + red[3][4][o];
      float ahn = b_hh[2 * DDIM + o] + red[0][5][o] + red[1][5][o] + red[2][5][o] + red[3][5][o];
      float rg = 1.f / (1.f + expf(-(air + ahr)));
      float zg = 1.f / (1.f + expf(-(aiz + ahz)));
      float ng = tanhf(ain + rg * ahn);
      float nh = (1.f - zg) * ng + zg * sh[o];
      v1[o] = nh;
      float s2 = nh, ss2 = nh * nh;
      wave_reduce2(s2, ss2);
      if (lane == 0) { scal[wid] = s2; scal[4 + wid] = ss2; }
    }
    __syncthreads();
    if (ks == 0) {
      float sS = scal[0] + scal[1] + scal[2] + scal[3];
      float sQ = scal[4] + scal[5] + scal[6] + scal[7];
      float m = sS * (1.f / DDIM);
      float rs = rsqrtf(sQ * (1.f / DDIM) - m * m + LN_EPS_C);
      v2[o] = (v1[o] - m) * rs * g_ff[o] + be_ff[o];
    }
    __syncthreads();
    {
      float p = 0.f;
      const __half* wp = W1T + (size_t)(ks * 64) * DDIM + o;
#pragma unroll 8
      for (int dd = 0; dd < 64; ++dd)
        p = fmaf(v2[ks * 64 + dd], __half2float(wp[(size_t)dd * DDIM]), p);
      red[ks][0][o] = p;
    }
    __syncthreads();
    if (ks == 0)
      su[o] = fmaxf(b1[o] + red[0][0][o] + red[1][0][o] + red[2][0][o] + red[3][0][o], 0.f);
    __syncthreads();
    {
      float p = 0.f;
      const __half* wp = W2T + (size_t)(ks * 64) * DDIM + o;
#pragma unroll 8
      for (int dd = 0; dd < 64; ++dd)
        p = fmaf(su[ks * 64 + dd], __half2float(wp[(size_t)dd * DDIM]), p);
      red[ks][0][o] = p;
    }
    __syncthreads();
    if (ks == 0) {
      float out = v1[o] + b2[o] + red[0][0][o] + red[1][0][o] + red[2][0][o] + red[3][0][o];
      slots_out[(size_t)r * DDIM + o] = out;
      v2[o] = out;
    }
    __syncthreads();
  }
  if (!compute_qk) return;
  if (ks == 0) {
    float x = v2[o];
    float s2 = x, ss2 = x * x;
    wave_reduce2(s2, ss2);
    if (lane == 0) { scal[wid] = s2; scal[4 + wid] = ss2; }
  }
  __syncthreads();
  if (ks == 0) {
    float sS = scal[0] + scal[1] + scal[2] + scal[3];
    float sQ = scal[4] + scal[5] + scal[6] + scal[7];
    float m = sS * (1.f / DDIM);
    float rs = rsqrtf(sQ * (1.f / DDIM) - m * m + LN_EPS_C);
    su[o] = (v2[o] - m) * rs * g_sl[o] + be_sl[o];
  }
  __syncthreads();
  {
    float p = 0.f;
    const __half* wp = WqT + (size_t)(ks * 64) * DDIM + o;
#pragma unroll 8
    for (int dd = 0; dd < 64; ++dd)
      p = fmaf(su[ks * 64 + dd], __half2float(wp[(size_t)dd * DDIM]), p);
    red[ks][0][o] = p;
  }
  __syncthreads();
  if (ks == 0)
    sh[o] = bq[o] + red[0][0][o] + red[1][0][o] + red[2][0][o] + red[3][0][o];
  __syncthreads();
  {
    float p = 0.f;
    const __half* wp = Wk_h + (size_t)(ks * 64) * DDIM + o;
#pragma unroll 8
    for (int dd = 0; dd < 64; ++dd)
      p = fmaf(sh[ks * 64 + dd], __half2float(wp[(size_t)dd * DDIM]), p);
    red[ks][0][o] = p;
  }
  __syncthreads();
  if (ks == 0) {
    float qkv = SCALE * (red[0][0][o] + red[1][0][o] + red[2][0][o] + red[3][0][o]);
    qk[(size_t)r * DDIM + o] = qkv;
    float v0 = sh[o] * bk[o], d1 = 0.f;
    wave_reduce2(v0, d1);
    if (lane == 0) scal[wid] = v0;
  }
  __syncthreads();
  if (t == 0)
    qkb_out[r] = SCALE * (scal[0] + scal[1] + scal[2] + scal[3]);
}

extern "C" void kernel_launch(void* const* d_in, const int* in_sizes, int n_in,
                              void* d_out, int out_size, void* d_ws,
                              size_t ws_size, hipStream_t stream) {
  const float* inputs   = (const float*)d_in[0];
  const float* noise    = (const float*)d_in[1];
  const float* slots_mu = (const float*)d_in[2];
  const float* slots_ls = (const float*)d_in[3];
  const float* Wq   = (const float*)d_in[4];
  const float* bq   = (const float*)d_in[5];
  const float* Wk   = (const float*)d_in[6];
  const float* bk   = (const float*)d_in[7];
  const float* Wv   = (const float*)d_in[8];
  const float* bv   = (const float*)d_in[9];
  const float* W_ih = (const float*)d_in[10];
  const float* W_hh = (const float*)d_in[11];
  const float* b_ih = (const float*)d_in[12];
  const float* b_hh = (const float*)d_in[13];
  const float* W1   = (const float*)d_in[14];
  const float* b1   = (const float*)d_in[15];
  const float* W2   = (const float*)d_in[16];
  const float* b2   = (const float*)d_in[17];
  const float* g_in = (const float*)d_in[18];
  const float* be_in= (const float*)d_in[19];
  const float* g_sl = (const float*)d_in[20];
  const float* be_sl= (const float*)d_in[21];
  const float* g_ff = (const float*)d_in[22];
  const float* be_ff= (const float*)d_in[23];

  float* out_slots = (float*)d_out;                 // [32,8,256]
  float* out_attn  = (float*)d_out + SROWS * DDIM;  // [32,8,4096]

  float* w = (float*)d_ws;
  float* slots = w;  w += SROWS * DDIM;
  float* qk = w;     w += SROWS * DDIM;
  float* qkb = w;    w += SROWS;
  float* S_part = w; w += NBATCH * NCHK * NSLOT;   // 16384
  __half* h = (__half*)w;
  __half* xh = h;     h += (size_t)NROWS * DDIM;                  // 67 MB
  __half* u_part = h; h += (size_t)NBATCH * NCHK * NSLOT * DDIM;  // 8.4 MB
  __half* WqT_h = h;  h += DDIM * DDIM;
  __half* WvT_h = h;  h += DDIM * DDIM;
  __half* WihT_h = h; h += DDIM * 3 * DDIM;
  __half* WhhT_h = h; h += DDIM * 3 * DDIM;
  __half* W1T_h = h;  h += DDIM * DDIM;
  __half* W2T_h = h;  h += DDIM * DDIM;
  __half* Wk_h = h;   h += DDIM * DDIM;
  // total ws ~ 80 MB

  convert_weights_k<<<dim3(88, 8), 256, 0, stream>>>(
      Wq, Wv, W_ih, W_hh, W1, W2, Wk, WqT_h, WvT_h, WihT_h, WhhT_h, W1T_h,
      W2T_h, Wk_h);
  // init: slots from noise + qk/qkb
  slot_update_k<<<SROWS, 1024, 0, stream>>>(
      u_part, S_part, slots, WvT_h, bv, WihT_h, WhhT_h, b_ih, b_hh, g_ff,
      be_ff, W1T_h, b1, W2T_h, b2, g_sl, be_sl, WqT_h, bq, Wk_h, bk, noise,
      slots_mu, slots_ls, slots, qk, qkb, 1, 1);
  xh_prep_k<<<NROWS / 4, 256, 0, stream>>>(inputs, g_in, be_in, xh);
  for (int it = 0; it < 3; ++it) {
    fused_attn_f16_k<<<dim3(NBATCH, 16), 256, 0, stream>>>(
        xh, qk, qkb, out_attn, S_part, u_part, (it == 2) ? 1 : 0);
    float* sout = (it == 2) ? out_slots : slots;
    slot_update_k<<<SROWS, 1024, 0, stream>>>(
        u_part, S_part, slots, WvT_h, bv, WihT_h, WhhT_h, b_ih, b_hh, g_ff,
        be_ff, W1T_h, b1, W2T_h, b2, g_sl, be_sl, WqT_h, bq, Wk_h, bk, noise,
        slots_mu, slots_ls, sout, qk, qkb, 0, (it == 2) ? 0 : 1);
  }
}

// Round 11
// 270.097 us; speedup vs baseline: 1.0382x; 1.0382x over previous
//
#include <hip/hip_runtime.h>
#include <hip/hip_fp16.h>
#include <cstdint>
#include <cstddef>

// SlotAttention, round 10.
//  - token pass split into TWO streaming kernels (no block-phase barriers):
//    dots_k: 16 lanes/token, qk in packed-fp16 regs, v_dot2_f32_f16 dots,
//            shfl butterfly, redundant softmax, ae fp16 + S partials out.
//    update_k: stage ae chunk (1 barrier), stream xh coalesced, 8 fma/load,
//            256 tokens/block accumulated, u_part fp16 out; attn on last iter.
//  - xh_prep / convert_weights / slot_update proven (r6-r8); slot_update
//    phase-0/S adjusted for 16 u-groups / 32 S-parts.

#define NTOK 4096
#define DDIM 256
#define NSLOT 8
#define NBATCH 32
#define SROWS (NBATCH * NSLOT)
#define NROWS (NBATCH * NTOK)
#define SCALE 0.0625f
#define LN_EPS_C 1e-5f
#define ATTN_EPS_C 1e-8f

typedef _Float16 f16x2 __attribute__((ext_vector_type(2)));

__device__ __forceinline__ f16x2 u2h(unsigned u) {
  union { unsigned u; f16x2 h; } c;
  c.u = u;
  return c.h;
}

__device__ __forceinline__ void wave_reduce2(float& s, float& ss) {
#pragma unroll
  for (int off = 32; off > 0; off >>= 1) {
    s  += __shfl_down(s, off, 64);
    ss += __shfl_down(ss, off, 64);
  }
}
__device__ __forceinline__ void wave_reduce2_xor(float& s, float& ss) {
#pragma unroll
  for (int off = 32; off > 0; off >>= 1) {
    s  += __shfl_xor(s, off, 64);
    ss += __shfl_xor(ss, off, 64);
  }
}

// transpose 6 weight matrices to fp16; plain-convert Wk to fp16 (r6 proven).
__global__ __launch_bounds__(256) void convert_weights_k(
    const float* __restrict__ Wq, const float* __restrict__ Wv,
    const float* __restrict__ Wih, const float* __restrict__ Whh,
    const float* __restrict__ W1, const float* __restrict__ W2,
    const float* __restrict__ Wk, __half* __restrict__ WqT,
    __half* __restrict__ WvT, __half* __restrict__ WihT,
    __half* __restrict__ WhhT, __half* __restrict__ W1T,
    __half* __restrict__ W2T, __half* __restrict__ Wk_h) {
  __shared__ float tile[32][33];
  int bz = blockIdx.x;
  int tx = threadIdx.x & 31, ty = threadIdx.x >> 5;
  if (bz >= 80) {
    int ro = (bz - 80) * 32, cd = blockIdx.y * 32;
#pragma unroll
    for (int p = 0; p < 32; p += 8)
      Wk_h[(size_t)(ro + ty + p) * DDIM + cd + tx] =
          __float2half(Wk[(size_t)(ro + ty + p) * DDIM + cd + tx]);
    return;
  }
  const float* in; __half* out; int O, bo;
  if (bz < 8)       { in = Wq;  out = WqT;  O = 256; bo = bz; }
  else if (bz < 16) { in = Wv;  out = WvT;  O = 256; bo = bz - 8; }
  else if (bz < 40) { in = Wih; out = WihT; O = 768; bo = bz - 16; }
  else if (bz < 64) { in = Whh; out = WhhT; O = 768; bo = bz - 40; }
  else if (bz < 72) { in = W1;  out = W1T;  O = 256; bo = bz - 64; }
  else              { in = W2;  out = W2T;  O = 256; bo = bz - 72; }
  int ro = bo * 32, cd = blockIdx.y * 32;
#pragma unroll
  for (int p = 0; p < 32; p += 8)
    tile[ty + p][tx] = in[(size_t)(ro + ty + p) * DDIM + cd + tx];
  __syncthreads();
#pragma unroll
  for (int p = 0; p < 32; p += 8)
    out[(size_t)(cd + ty + p) * O + ro + tx] = __float2half(tile[tx][ty + p]);
}

// streaming LN -> fp16. wave per row (64 lanes x float4 = 256 floats).
__global__ __launch_bounds__(256) void xh_prep_k(
    const float* __restrict__ X, const float* __restrict__ g,
    const float* __restrict__ be, __half* __restrict__ xh) {
  int row = blockIdx.x * 4 + (threadIdx.x >> 6);
  int lane = threadIdx.x & 63;
  float4 a = *(const float4*)(X + (size_t)row * DDIM + lane * 4);
  float s = a.x + a.y + a.z + a.w;
  float ss = a.x * a.x + a.y * a.y + a.z * a.z + a.w * a.w;
  wave_reduce2_xor(s, ss);
  float m = s * (1.f / DDIM);
  float rs = rsqrtf(ss * (1.f / DDIM) - m * m + LN_EPS_C);
  float4 gv = *(const float4*)(g + lane * 4);
  float4 bev = *(const float4*)(be + lane * 4);
  union { __half2 h[2]; uint2 u; } pk;
  pk.h[0] = __floats2half2_rn((a.x - m) * rs * gv.x + bev.x,
                              (a.y - m) * rs * gv.y + bev.y);
  pk.h[1] = __floats2half2_rn((a.z - m) * rs * gv.z + bev.z,
                              (a.w - m) * rs * gv.w + bev.w);
  *(uint2*)(xh + (size_t)row * DDIM + lane * 4) = pk.u;
}

// dots + softmax, streaming. Block = (batch b, group g of 128 tokens).
// Lane: sub = lane>>4 (token within wave quad), r = lane&15 (16-dim group).
// qk in packed-fp16 registers; v_dot2_f32_f16 accumulation; butterfly over r.
__global__ __launch_bounds__(256) void dots_k(
    const __half* __restrict__ xh, const float* __restrict__ qk,
    const float* __restrict__ qkb, __half* __restrict__ ae_g,
    float* __restrict__ S_part) {
  __shared__ float red[4][8];
  int b = blockIdx.x, g = blockIdx.y, t = threadIdx.x;
  int w = t >> 6, lane = t & 63;
  int sub = lane >> 4, r = lane & 15;
  // qk -> packed fp16 regs: qk2[i][d2] covers dims r*16 + d2*2, +1
  f16x2 qk2[NSLOT][8];
#pragma unroll
  for (int i = 0; i < NSLOT; ++i) {
    const float* qr = qk + ((size_t)b * NSLOT + i) * DDIM + r * 16;
#pragma unroll
    for (int d4 = 0; d4 < 4; ++d4) {
      float4 q4 = *(const float4*)(qr + d4 * 4);
      qk2[i][d4 * 2] = (f16x2){(_Float16)q4.x, (_Float16)q4.y};
      qk2[i][d4 * 2 + 1] = (f16x2){(_Float16)q4.z, (_Float16)q4.w};
    }
  }
  float qkb_r[NSLOT];
#pragma unroll
  for (int i = 0; i < NSLOT; ++i) qkb_r[i] = qkb[b * NSLOT + i];
  float sacc = 0.f;
  const size_t tokbase = (size_t)b * NTOK + (size_t)g * 128;
  for (int it = 0; it < 8; ++it) {
    int tok = it * 16 + w * 4 + sub;
    const __half* xr = xh + (tokbase + tok) * DDIM + r * 16;
    uint4 v0 = *(const uint4*)(xr);
    uint4 v1 = *(const uint4*)(xr + 8);
    f16x2 x2[8];
    x2[0] = u2h(v0.x); x2[1] = u2h(v0.y); x2[2] = u2h(v0.z); x2[3] = u2h(v0.w);
    x2[4] = u2h(v1.x); x2[5] = u2h(v1.y); x2[6] = u2h(v1.z); x2[7] = u2h(v1.w);
    float p[NSLOT];
#pragma unroll
    for (int i = 0; i < NSLOT; ++i) {
      float s = 0.f;
#pragma unroll
      for (int d2 = 0; d2 < 8; ++d2)
        s = __builtin_amdgcn_fdot2(x2[d2], qk2[i][d2], s, false);
      p[i] = s;
    }
#pragma unroll
    for (int i = 0; i < NSLOT; ++i) {
      p[i] += __shfl_xor(p[i], 1, 64);
      p[i] += __shfl_xor(p[i], 2, 64);
      p[i] += __shfl_xor(p[i], 4, 64);
      p[i] += __shfl_xor(p[i], 8, 64);
      p[i] += qkb_r[i];
    }
    float mx = -1e30f;
#pragma unroll
    for (int i = 0; i < NSLOT; ++i) mx = fmaxf(mx, p[i]);
    float sum = 0.f;
#pragma unroll
    for (int i = 0; i < NSLOT; ++i) { p[i] = expf(p[i] - mx); sum += p[i]; }
    float inv = 1.f / sum;
    if (r < NSLOT) {
      float ae = p[r] * inv + ATTN_EPS_C;
      ae_g[(tokbase + tok) * NSLOT + r] = __float2half(ae);
      sacc += ae;
    }
  }
  // S partial: combine subs (all lanes active for shfl), then waves via LDS
  sacc += __shfl_down(sacc, 32, 64);
  sacc += __shfl_down(sacc, 16, 64);
  if (lane < NSLOT) red[w][lane] = sacc;
  __syncthreads();
  if (t < NSLOT) {
    float s = red[0][t] + red[1][t] + red[2][t] + red[3][t];
    S_part[((size_t)b * 32 + g) * NSLOT + t] = s;
  }
}

// u accumulation, streaming. Block = (batch b, group g of 256 tokens).
// thread = dim; ae chunk staged once (1 barrier); coalesced xh loads.
__global__ __launch_bounds__(256) void update_k(
    const __half* __restrict__ xh, const __half* __restrict__ ae_g,
    float* __restrict__ attn_out, __half* __restrict__ u_part,
    int write_attn) {
  __shared__ __align__(16) __half sa[256 * NSLOT];  // [token][slot] 4KB
  int b = blockIdx.x, g = blockIdx.y, t = threadIdx.x;
  const size_t tokbase = (size_t)b * NTOK + (size_t)g * 256;
  *(uint4*)&sa[t * 8] = *(const uint4*)(ae_g + tokbase * NSLOT + t * 8);
  __syncthreads();
  float acc[NSLOT] = {};
  const __half* xb = xh + tokbase * DDIM + t;
#pragma unroll 8
  for (int jj = 0; jj < 256; ++jj) {
    float x = __half2float(xb[(size_t)jj * DDIM]);
    const __half2* a2 = (const __half2*)&sa[jj * 8];
    float2 f0 = __half22float2(a2[0]);
    float2 f1 = __half22float2(a2[1]);
    float2 f2 = __half22float2(a2[2]);
    float2 f3 = __half22float2(a2[3]);
    acc[0] = fmaf(x, f0.x, acc[0]);
    acc[1] = fmaf(x, f0.y, acc[1]);
    acc[2] = fmaf(x, f1.x, acc[2]);
    acc[3] = fmaf(x, f1.y, acc[3]);
    acc[4] = fmaf(x, f2.x, acc[4]);
    acc[5] = fmaf(x, f2.y, acc[5]);
    acc[6] = fmaf(x, f3.x, acc[6]);
    acc[7] = fmaf(x, f3.y, acc[7]);
  }
  __half* upb = u_part + (((size_t)b * 16 + g) * NSLOT) * DDIM + t;
#pragma unroll
  for (int i = 0; i < NSLOT; ++i) upb[(size_t)i * DDIM] = __float2half(acc[i]);
  if (write_attn) {
#pragma unroll
    for (int i = 0; i < NSLOT; ++i)
      attn_out[((size_t)b * NSLOT + i) * NTOK + g * 256 + t] =
          __half2float(sa[t * 8 + i]) - ATTN_EPS_C;
  }
}

// slot path, 1024 threads: o = t&255, ks = t>>8. fp16 weights. (r6-r8 proven;
// phase-0 reads 16 u-groups, S reduce over 32 parts)
__global__ __launch_bounds__(1024) void slot_update_k(
    const __half* __restrict__ u_part, const float* __restrict__ S_part,
    const float* __restrict__ slots_in, const __half* __restrict__ WvT,
    const float* __restrict__ bv, const __half* __restrict__ WihT,
    const __half* __restrict__ WhhT, const float* __restrict__ b_ih,
    const float* __restrict__ b_hh, const float* __restrict__ g_ff,
    const float* __restrict__ be_ff, const __half* __restrict__ W1T,
    const float* __restrict__ b1, const __half* __restrict__ W2T,
    const float* __restrict__ b2, const float* __restrict__ g_sl,
    const float* __restrict__ be_sl, const __half* __restrict__ WqT,
    const float* __restrict__ bq, const __half* __restrict__ Wk_h,
    const float* __restrict__ bk, const float* __restrict__ noise,
    const float* __restrict__ mu, const float* __restrict__ logsig,
    float* __restrict__ slots_out, float* __restrict__ qk,
    float* __restrict__ qkb_out, int init, int compute_qk) {
  __shared__ float red[4][6][DDIM];
  __shared__ float su[DDIM], sh[DDIM], supd[DDIM], v1[DDIM], v2[DDIM];
  __shared__ float scal[16];
  int r = blockIdx.x, t = threadIdx.x;
  int b = r >> 3, i = r & 7;
  int o = t & 255, ks = t >> 8;
  int lane = t & 63, wid = t >> 6;
  if (init) {
    if (ks == 0) {
      float ns = mu[o] + expf(logsig[o]) * noise[(size_t)r * DDIM + o];
      slots_out[(size_t)r * DDIM + o] = ns;
      v2[o] = ns;
    }
    __syncthreads();
  } else {
    {
      float up = 0.f;
      const __half* upp =
          u_part + (((size_t)b * 16 + ks * 4) * NSLOT + i) * DDIM + o;
#pragma unroll
      for (int cc = 0; cc < 4; ++cc)
        up += __half2float(upp[(size_t)cc * (NSLOT * DDIM)]);
      red[ks][0][o] = up;
    }
    if (t < 64) {
      float sp = (t < 32) ? S_part[((size_t)b * 32 + t) * NSLOT + i] : 0.f;
#pragma unroll
      for (int off = 16; off > 0; off >>= 1) sp += __shfl_down(sp, off, 64);
      if (t == 0) scal[0] = sp;
    }
    if (ks == 0) sh[o] = slots_in[(size_t)r * DDIM + o];
    __syncthreads();
    if (ks == 0) {
      float invS = 1.f / scal[0];
      su[o] = (red[0][0][o] + red[1][0][o] + red[2][0][o] + red[3][0][o]) * invS;
    }
    __syncthreads();
    {
      float p = 0.f;
      const __half* wp = WvT + (size_t)(ks * 64) * DDIM + o;
#pragma unroll 8
      for (int dd = 0; dd < 64; ++dd)
        p = fmaf(su[ks * 64 + dd], __half2float(wp[(size_t)dd * DDIM]), p);
      red[ks][0][o] = p;
    }
    __syncthreads();
    if (ks == 0)
      supd[o] = bv[o] + red[0][0][o] + red[1][0][o] + red[2][0][o] + red[3][0][o];
    __syncthreads();
    {
      float p0 = 0, p1 = 0, p2 = 0, p3 = 0, p4 = 0, p5 = 0;
      const __half* pi = WihT + (size_t)(ks * 64) * (3 * DDIM) + o;
      const __half* ph = WhhT + (size_t)(ks * 64) * (3 * DDIM) + o;
#pragma unroll 4
      for (int dd = 0; dd < 64; ++dd) {
        float ud = supd[ks * 64 + dd], hd = sh[ks * 64 + dd];
        size_t off = (size_t)dd * (3 * DDIM);
        p0 = fmaf(ud, __half2float(pi[off]), p0);
        p1 = fmaf(ud, __half2float(pi[off + DDIM]), p1);
        p2 = fmaf(ud, __half2float(pi[off + 2 * DDIM]), p2);
        p3 = fmaf(hd, __half2float(ph[off]), p3);
        p4 = fmaf(hd, __half2float(ph[off + DDIM]), p4);
        p5 = fmaf(hd, __half2float(ph[off + 2 * DDIM]), p5);
      }
      red[ks][0][o] = p0; red[ks][1][o] = p1; red[ks][2][o] = p2;
      red[ks][3][o] = p3; red[ks][4][o] = p4; red[ks][5][o] = p5;
    }
    __syncthreads();
    if (ks == 0) {
      float air = b_ih[o] + red[0][0][o] + red[1][0][o] + red[2][0][o] + red[3][0][o];
      float aiz = b_ih[DDIM + o] + red[0][1][o] + red[1][1][o] + red[2][1][o] + red[3][1][o];
      float ain = b_ih[2 * DDIM + o] + red[0][2][o] + red[1][2][o] + red[2][2][o] + red[3][2][o];
      float ahr = b_hh[o] + red[0][3][o] + red[1][3][o] + red[2][3][o] + red[3][3][o];
      float ahz = b_hh[DDIM + o] + red[0][4][o] + red[1][4][o] + red[2][4][o] + red[3][4][o];
      float ahn = b_hh[2 * DDIM + o] + red[0][5][o] + red[1][5][o] + red[2][5][o] + red[3][5][o];
      float rg = 1.f / (1.f + expf(-(air + ahr)));
      float zg = 1.f / (1.f + expf(-(aiz + ahz)));
      float ng = tanhf(ain + rg * ahn);
      float nh = (1.f - zg) * ng + zg * sh[o];
      v1[o] = nh;
      float s2 = nh, ss2 = nh * nh;
      wave_reduce2(s2, ss2);
      if (lane == 0) { scal[wid] = s2; scal[4 + wid] = ss2; }
    }
    __syncthreads();
    if (ks == 0) {
      float sS = scal[0] + scal[1] + scal[2] + scal[3];
      float sQ = scal[4] + scal[5] + scal[6] + scal[7];
      float m = sS * (1.f / DDIM);
      float rs = rsqrtf(sQ * (1.f / DDIM) - m * m + LN_EPS_C);
      v2[o] = (v1[o] - m) * rs * g_ff[o] + be_ff[o];
    }
    __syncthreads();
    {
      float p = 0.f;
      const __half* wp = W1T + (size_t)(ks * 64) * DDIM + o;
#pragma unroll 8
      for (int dd = 0; dd < 64; ++dd)
        p = fmaf(v2[ks * 64 + dd], __half2float(wp[(size_t)dd * DDIM]), p);
      red[ks][0][o] = p;
    }
    __syncthreads();
    if (ks == 0)
      su[o] = fmaxf(b1[o] + red[0][0][o] + red[1][0][o] + red[2][0][o] + red[3][0][o], 0.f);
    __syncthreads();
    {
      float p = 0.f;
      const __half* wp = W2T + (size_t)(ks * 64) * DDIM + o;
#pragma unroll 8
      for (int dd = 0; dd < 64; ++dd)
        p = fmaf(su[ks * 64 + dd], __half2float(wp[(size_t)dd * DDIM]), p);
      red[ks][0][o] = p;
    }
    __syncthreads();
    if (ks == 0) {
      float out = v1[o] + b2[o] + red[0][0][o] + red[1][0][o] + red[2][0][o] + red[3][0][o];
      slots_out[(size_t)r * DDIM + o] = out;
      v2[o] = out;
    }
    __syncthreads();
  }
  if (!compute_qk) return;
  if (ks == 0) {
    float x = v2[o];
    float s2 = x, ss2 = x * x;
    wave_reduce2(s2, ss2);
    if (lane == 0) { scal[wid] = s2; scal[4 + wid] = ss2; }
  }
  __syncthreads();
  if (ks == 0) {
    float sS = scal[0] + scal[1] + scal[2] + scal[3];
    float sQ = scal[4] + scal[5] + scal[6] + scal[7];
    float m = sS * (1.f / DDIM);
    float rs = rsqrtf(sQ * (1.f / DDIM) - m * m + LN_EPS_C);
    su[o] = (v2[o] - m) * rs * g_sl[o] + be_sl[o];
  }
  __syncthreads();
  {
    float p = 0.f;
    const __half* wp = WqT + (size_t)(ks * 64) * DDIM + o;
#pragma unroll 8
    for (int dd = 0; dd < 64; ++dd)
      p = fmaf(su[ks * 64 + dd], __half2float(wp[(size_t)dd * DDIM]), p);
    red[ks][0][o] = p;
  }
  __syncthreads();
  if (ks == 0)
    sh[o] = bq[o] + red[0][0][o] + red[1][0][o] + red[2][0][o] + red[3][0][o];
  __syncthreads();
  {
    float p = 0.f;
    const __half* wp = Wk_h + (size_t)(ks * 64) * DDIM + o;
#pragma unroll 8
    for (int dd = 0; dd < 64; ++dd)
      p = fmaf(sh[ks * 64 + dd], __half2float(wp[(size_t)dd * DDIM]), p);
    red[ks][0][o] = p;
  }
  __syncthreads();
  if (ks == 0) {
    float qkv = SCALE * (red[0][0][o] + red[1][0][o] + red[2][0][o] + red[3][0][o]);
    qk[(size_t)r * DDIM + o] = qkv;
    float v0 = sh[o] * bk[o], d1 = 0.f;
    wave_reduce2(v0, d1);
    if (lane == 0) scal[wid] = v0;
  }
  __syncthreads();
  if (t == 0)
    qkb_out[r] = SCALE * (scal[0] + scal[1] + scal[2] + scal[3]);
}

extern "C" void kernel_launch(void* const* d_in, const int* in_sizes, int n_in,
                              void* d_out, int out_size, void* d_ws,
                              size_t ws_size, hipStream_t stream) {
  const float* inputs   = (const float*)d_in[0];
  const float* noise    = (const float*)d_in[1];
  const float* slots_mu = (const float*)d_in[2];
  const float* slots_ls = (const float*)d_in[3];
  const float* Wq   = (const float*)d_in[4];
  const float* bq   = (const float*)d_in[5];
  const float* Wk   = (const float*)d_in[6];
  const float* bk   = (const float*)d_in[7];
  const float* Wv   = (const float*)d_in[8];
  const float* bv   = (const float*)d_in[9];
  const float* W_ih = (const float*)d_in[10];
  const float* W_hh = (const float*)d_in[11];
  const float* b_ih = (const float*)d_in[12];
  const float* b_hh = (const float*)d_in[13];
  const float* W1   = (const float*)d_in[14];
  const float* b1   = (const float*)d_in[15];
  const float* W2   = (const float*)d_in[16];
  const float* b2   = (const float*)d_in[17];
  const float* g_in = (const float*)d_in[18];
  const float* be_in= (const float*)d_in[19];
  const float* g_sl = (const float*)d_in[20];
  const float* be_sl= (const float*)d_in[21];
  const float* g_ff = (const float*)d_in[22];
  const float* be_ff= (const float*)d_in[23];

  float* out_slots = (float*)d_out;                 // [32,8,256]
  float* out_attn  = (float*)d_out + SROWS * DDIM;  // [32,8,4096]

  float* w = (float*)d_ws;
  float* slots = w;  w += SROWS * DDIM;
  float* qk = w;     w += SROWS * DDIM;
  float* qkb = w;    w += SROWS;
  float* S_part = w; w += NBATCH * 32 * NSLOT;     // 8192
  __half* h = (__half*)w;
  __half* xh = h;     h += (size_t)NROWS * DDIM;                 // 67 MB
  __half* u_part = h; h += (size_t)NBATCH * 16 * NSLOT * DDIM;   // 2 MB
  __half* ae_g = h;   h += (size_t)NROWS * NSLOT;                // 2 MB
  __half* WqT_h = h;  h += DDIM * DDIM;
  __half* WvT_h = h;  h += DDIM * DDIM;
  __half* WihT_h = h; h += DDIM * 3 * DDIM;
  __half* WhhT_h = h; h += DDIM * 3 * DDIM;
  __half* W1T_h = h;  h += DDIM * DDIM;
  __half* W2T_h = h;  h += DDIM * DDIM;
  __half* Wk_h = h;   h += DDIM * DDIM;
  // total ws ~ 76 MB

  convert_weights_k<<<dim3(88, 8), 256, 0, stream>>>(
      Wq, Wv, W_ih, W_hh, W1, W2, Wk, WqT_h, WvT_h, WihT_h, WhhT_h, W1T_h,
      W2T_h, Wk_h);
  slot_update_k<<<SROWS, 1024, 0, stream>>>(
      u_part, S_part, slots, WvT_h, bv, WihT_h, WhhT_h, b_ih, b_hh, g_ff,
      be_ff, W1T_h, b1, W2T_h, b2, g_sl, be_sl, WqT_h, bq, Wk_h, bk, noise,
      slots_mu, slots_ls, slots, qk, qkb, 1, 1);
  xh_prep_k<<<NROWS / 4, 256, 0, stream>>>(inputs, g_in, be_in, xh);
  for (int it = 0; it < 3; ++it) {
    dots_k<<<dim3(NBATCH, 32), 256, 0, stream>>>(xh, qk, qkb, ae_g, S_part);
    update_k<<<dim3(NBATCH, 16), 256, 0, stream>>>(
        xh, ae_g, out_attn, u_part, (it == 2) ? 1 : 0);
    float* sout = (it == 2) ? out_slots : slots;
    slot_update_k<<<SROWS, 1024, 0, stream>>>(
        u_part, S_part, slots, WvT_h, bv, WihT_h, WhhT_h, b_ih, b_hh, g_ff,
        be_ff, W1T_h, b1, W2T_h, b2, g_sl, be_sl, WqT_h, bq, Wk_h, bk, noise,
        slots_mu, slots_ls, sout, qk, qkb, 0, (it == 2) ? 0 : 1);
  }
}